// Round 1
// baseline (129.197 us; speedup 1.0000x reference)
//
#include <hip/hip_runtime.h>

// StackedLinear (LSQ-quantized, 8 classes x [32 x 1024]), B=8192.
// out[b,o] = alpha[c,o] * sum_i w_int[c,o,i] * x[b,i] + bias[c,o],  c = idx[b]
// w_int = rint(clip(w/alpha, -128, 127)) is an integer in [-128,127] ->
// EXACT in bf16, so bf16 MFMA with alpha applied in the epilogue only loses
// x->bf16 rounding (~1e-3 absmax vs 6.6e-2 threshold).
//
// Pipeline (3 graph nodes):
//   1. hipMemsetAsync: zero 8 class counters in ws
//   2. bucket_kernel : detect int64-vs-int32 index width, bucket samples by class
//   3. gemm_kernel   : per-class tiled GEMM (M=16,N=32,K=1024), MFMA 16x16x32 bf16,
//                      quantization fused into W staging (weights L2-resident)

#define IN_F   1024
#define OUT_F  32
#define NCLS   8
#define NB     8192
#define TILE_M 16
#define BK     128
#define LDSP   (BK + 8)   // +16B row pad -> even bank spread for b128 frag reads

typedef __attribute__((ext_vector_type(8))) __bf16 bf16x8;
typedef __attribute__((ext_vector_type(4))) float  f32x4;

__device__ __forceinline__ unsigned short f2bf(float f) {
    // round-to-nearest-even f32 -> bf16 (no NaN handling needed here)
    unsigned int u = __builtin_bit_cast(unsigned int, f);
    u += 0x7FFFu + ((u >> 16) & 1u);
    return (unsigned short)(u >> 16);
}

// ---------------------------------------------------------------------------
// Bucket samples by class. ls buffer may be int64 (JAX x64 on) or int32
// (default JAX demotes astype(int64)). Detect: values are 0..7, so for int64
// every odd 32-bit word is 0; for int32 the odd words are random 0..7
// (P(all zero) = 8^-4096 ~ 0).
__global__ __launch_bounds__(256) void bucket_kernel(
    const unsigned int* __restrict__ lsw,
    int* __restrict__ counts, int* __restrict__ buckets)
{
    __shared__ int lcnt[NCLS];
    __shared__ int lbase[NCLS];
    __shared__ int s_is64;
    int t = threadIdx.x;
    int b = blockIdx.x * 256 + t;
    if (t < NCLS) lcnt[t] = 0;
    if (t == 0) s_is64 = 1;
    __syncthreads();
    int bad = 0;
    for (int i = t; i < NB / 2; i += 256) bad |= (lsw[2 * i + 1] != 0u);
    if (bad) atomicAnd(&s_is64, 0);
    __syncthreads();
    int c = s_is64 ? (int)lsw[2 * b] : (int)lsw[b];
    int lpos = atomicAdd(&lcnt[c], 1);
    __syncthreads();
    if (t < NCLS) lbase[t] = atomicAdd(&counts[t], lcnt[t]);
    __syncthreads();
    buckets[c * NB + lbase[c] + lpos] = b;
}

// ---------------------------------------------------------------------------
// Per-class GEMM tile: 16 samples x 32 outputs x K=1024.
// Block = 128 threads = 2 waves; wave w owns n-tile (outputs 16w..16w+15).
// MFMA 16x16x32 bf16 layouts (verified m89/m91):
//   A[m=lane&15][k=(lane>>4)*8+j], B^T[n=lane&15][k=(lane>>4)*8+j],
//   D: col(n)=lane&15, row(m)=(lane>>4)*4+reg.
__global__ __launch_bounds__(128) void gemm_kernel(
    const float* __restrict__ x, const float* __restrict__ weight,
    const float* __restrict__ bias, const float* __restrict__ law,
    const int* __restrict__ counts, const int* __restrict__ buckets,
    float* __restrict__ out)
{
    int c = blockIdx.y;
    int cnt = counts[c];
    int start = blockIdx.x * TILE_M;
    if (start >= cnt) return;                 // inactive tile

    __shared__ unsigned short Xs[TILE_M][LDSP];
    __shared__ unsigned short Ws[OUT_F][LDSP];
    __shared__ int   sid[TILE_M];
    __shared__ float alf[OUT_F];

    int t = threadIdx.x;
    int nvalid = min(TILE_M, cnt - start);
    if (t < TILE_M) {
        int j = min(t, nvalid - 1);           // clamp: dup a valid row, never stored
        sid[t] = buckets[c * NB + start + j];
    }
    if (t < OUT_F) alf[t] = expf(law[c * OUT_F + t]);
    __syncthreads();

    int lane = t & 63;
    int wave = t >> 6;        // n-tile select (0 or 1)
    int fr   = lane & 15;
    int fq   = lane >> 4;
    f32x4 acc = {0.f, 0.f, 0.f, 0.f};

    for (int kc = 0; kc < IN_F / BK; ++kc) {
        // ---- stage X tile: 16 rows x 128 f32 -> bf16 (512 float4, 4/thread)
        #pragma unroll
        for (int q = 0; q < 4; ++q) {
            int f = q * 128 + t;
            int r = f >> 5, slot = f & 31;    // 32 consecutive lanes = 512B/row
            float4 v = *(const float4*)(x + (size_t)sid[r] * IN_F + kc * BK + slot * 4);
            ushort4 p;
            p.x = f2bf(v.x); p.y = f2bf(v.y); p.z = f2bf(v.z); p.w = f2bf(v.w);
            *(ushort4*)&Xs[r][slot * 4] = p;
        }
        // ---- stage W tile with fused LSQ quantization: 32 rows x 128 f32
        #pragma unroll
        for (int q = 0; q < 8; ++q) {
            int f = q * 128 + t;
            int r = f >> 5, slot = f & 31;
            float av = alf[r];
            float4 v = *(const float4*)(weight + (size_t)(c * OUT_F + r) * IN_F + kc * BK + slot * 4);
            ushort4 p;  // rint(clip(w/alpha)) is an integer in [-128,127]: exact in bf16
            p.x = f2bf(rintf(fminf(fmaxf(v.x / av, -128.f), 127.f)));
            p.y = f2bf(rintf(fminf(fmaxf(v.y / av, -128.f), 127.f)));
            p.z = f2bf(rintf(fminf(fmaxf(v.z / av, -128.f), 127.f)));
            p.w = f2bf(rintf(fminf(fmaxf(v.w / av, -128.f), 127.f)));
            *(ushort4*)&Ws[r][slot * 4] = p;
        }
        __syncthreads();
        // ---- MFMA: 4 K-steps of 32 per chunk
        #pragma unroll
        for (int kk = 0; kk < BK / 32; ++kk) {
            bf16x8 a = *(const bf16x8*)&Xs[fr][kk * 32 + fq * 8];
            bf16x8 bb = *(const bf16x8*)&Ws[wave * 16 + fr][kk * 32 + fq * 8];
            acc = __builtin_amdgcn_mfma_f32_16x16x32_bf16(a, bb, acc, 0, 0, 0);
        }
        __syncthreads();
    }

    // ---- epilogue: out[sid[m]][o] = alpha_o * acc + bias_o
    int o = wave * 16 + fr;
    float av = alf[o];
    float bv = bias[c * OUT_F + o];
    #pragma unroll
    for (int reg = 0; reg < 4; ++reg) {
        int m = fq * 4 + reg;
        if (m < nvalid)
            out[(size_t)sid[m] * OUT_F + o] = acc[reg] * av + bv;
    }
}

// ---------------------------------------------------------------------------
extern "C" void kernel_launch(void* const* d_in, const int* in_sizes, int n_in,
                              void* d_out, int out_size, void* d_ws, size_t ws_size,
                              hipStream_t stream)
{
    (void)in_sizes; (void)n_in; (void)out_size; (void)ws_size;
    const float*        x      = (const float*)d_in[0];
    const unsigned int* ls     = (const unsigned int*)d_in[1];
    const float*        weight = (const float*)d_in[2];
    const float*        bias   = (const float*)d_in[3];
    const float*        law    = (const float*)d_in[4];
    float*              out    = (float*)d_out;

    int* counts  = (int*)d_ws;          // 8 ints
    int* buckets = counts + NCLS;       // 8 * 8192 ints

    hipMemsetAsync(counts, 0, NCLS * sizeof(int), stream);
    bucket_kernel<<<32, 256, 0, stream>>>(ls, counts, buckets);
    gemm_kernel<<<dim3(NB / TILE_M, NCLS), 128, 0, stream>>>(
        x, weight, bias, law, counts, buckets, out);
}

// Round 2
// 96.279 us; speedup vs baseline: 1.3419x; 1.3419x over previous
//
#include <hip/hip_runtime.h>

// StackedLinear (LSQ-quantized, 8 classes x [32 x 1024]), B=8192.
// out[b,o] = alpha[c,o] * sum_i w_int[c,o,i] * x[b,i] + bias[c,o],  c = idx[b]
// w_int = rint(clip(w/alpha,-128,127)) is an integer in [-128,127] -> exact bf16.
//
// R2 design (latency-bound fix: R1 had 1 wave/SIMD + 16 barriers/block):
//   1. memset: zero 8 class counters
//   2. quantw: quantize W -> bf16 Wq[8][32][1024] (512KB, L2-resident) + alpha tab
//   3. bucket: int64/int32 detect, bucket samples by class, init out = bias
//   4. gemm  : split-K=4, 16 samples/wave, both n-halves, B-frags global->VGPR
//              (L2 hits), A-frags global->VGPR f32->bf16, NO LDS / NO barriers,
//              fp32 atomicAdd epilogue. ~2048 waves = 8 waves/CU.

#define IN_F   1024
#define OUT_F  32
#define NCLS   8
#define NB     8192
#define KSPLIT 4
#define KCH    (IN_F / KSPLIT)   // 256
#define GRIDX  48                // m-tile block slots per (class,ksplit); grid-stride

typedef __attribute__((ext_vector_type(8))) __bf16 bf16x8;
typedef __attribute__((ext_vector_type(4))) float  f32x4;

__device__ __forceinline__ unsigned short f2bf(float f) {
    unsigned int u = __builtin_bit_cast(unsigned int, f);
    u += 0x7FFFu + ((u >> 16) & 1u);
    return (unsigned short)(u >> 16);
}

__device__ __forceinline__ bf16x8 pack8(float4 v0, float4 v1) {
    union { unsigned short u[8]; bf16x8 v; } r;
    r.u[0] = f2bf(v0.x); r.u[1] = f2bf(v0.y); r.u[2] = f2bf(v0.z); r.u[3] = f2bf(v0.w);
    r.u[4] = f2bf(v1.x); r.u[5] = f2bf(v1.y); r.u[6] = f2bf(v1.z); r.u[7] = f2bf(v1.w);
    return r.v;
}

// ---------------------------------------------------------------------------
// One block per weight row (c*32+o): alpha = exp(law), w_int -> bf16.
__global__ __launch_bounds__(256) void quantw_kernel(
    const float* __restrict__ weight, const float* __restrict__ law,
    float* __restrict__ alf, unsigned short* __restrict__ wq)
{
    int row = blockIdx.x;                 // 0..255
    int t = threadIdx.x;
    float a = expf(law[row]);
    if (t == 0) alf[row] = a;
    float4 v = ((const float4*)(weight + (size_t)row * IN_F))[t];
    ushort4 p;
    p.x = f2bf(rintf(fminf(fmaxf(v.x / a, -128.f), 127.f)));
    p.y = f2bf(rintf(fminf(fmaxf(v.y / a, -128.f), 127.f)));
    p.z = f2bf(rintf(fminf(fmaxf(v.z / a, -128.f), 127.f)));
    p.w = f2bf(rintf(fminf(fmaxf(v.w / a, -128.f), 127.f)));
    ((ushort4*)(wq + (size_t)row * IN_F))[t] = p;
}

// ---------------------------------------------------------------------------
// Bucket by class + init out = bias[c]. Index width detect: values 0..7, so
// int64 => odd 32-bit words of the first 4096 elements (8192 words, within
// bounds for either width) are all zero; int32 => random 0..7 (P(all 0)=8^-4096).
__global__ __launch_bounds__(256) void bucket_kernel(
    const unsigned int* __restrict__ lsw, const float* __restrict__ bias,
    int* __restrict__ counts, unsigned short* __restrict__ buckets,
    float* __restrict__ out)
{
    __shared__ int lcnt[NCLS];
    __shared__ int lbase[NCLS];
    __shared__ int s_is64;
    int t = threadIdx.x;
    int b = blockIdx.x * 256 + t;
    if (t < NCLS) lcnt[t] = 0;
    if (t == 0) s_is64 = 1;
    __syncthreads();
    int bad = 0;
    for (int i = t; i < NB / 2; i += 256) bad |= (lsw[2 * i + 1] != 0u);
    if (bad) atomicAnd(&s_is64, 0);
    __syncthreads();
    int c = s_is64 ? (int)lsw[2 * b] : (int)lsw[b];
    // out[b][:] = bias[c][:]
    const float4* bb = (const float4*)(bias + c * OUT_F);
    float4* ob = (float4*)(out + (size_t)b * OUT_F);
    #pragma unroll
    for (int i = 0; i < OUT_F / 4; ++i) ob[i] = bb[i];
    int lpos = atomicAdd(&lcnt[c], 1);
    __syncthreads();
    if (t < NCLS) lbase[t] = atomicAdd(&counts[t], lcnt[t]);
    __syncthreads();
    buckets[c * NB + lbase[c] + lpos] = (unsigned short)b;
}

// ---------------------------------------------------------------------------
// Split-K GEMM, no LDS, no barriers. Block = 128 thr = 2 waves; each wave
// owns an m-tile of 16 samples, both n-halves (2 accs), K-chunk of 256.
// MFMA 16x16x32 bf16 layouts (verified R1): A[m=lane&15][k=q*8+j],
// B^T[n=lane&15][k=q*8+j], D: n=lane&15, m=q*4+reg.
__global__ __launch_bounds__(128) void gemm_kernel(
    const float* __restrict__ x, const float* __restrict__ alf,
    const unsigned short* __restrict__ wq,
    const int* __restrict__ counts, const unsigned short* __restrict__ buckets,
    float* __restrict__ out)
{
    int c  = blockIdx.y;
    int kq = blockIdx.z;
    int cnt = counts[c];
    int t = threadIdx.x;
    int wave = t >> 6, lane = t & 63;
    int fr = lane & 15, fq = lane >> 4;
    int k0 = kq * KCH;

    // B fragments for both n-halves, 8 k-steps, held in VGPRs (L2-hot loads)
    const unsigned short* wrow0 = wq + (size_t)(c * OUT_F + fr) * IN_F + k0 + fq * 8;
    const unsigned short* wrow1 = wrow0 + 16 * IN_F;
    bf16x8 Bf0[8], Bf1[8];
    #pragma unroll
    for (int kk = 0; kk < 8; ++kk) {
        Bf0[kk] = *(const bf16x8*)(wrow0 + kk * 32);
        Bf1[kk] = *(const bf16x8*)(wrow1 + kk * 32);
    }
    float a0 = alf[c * OUT_F + fr];
    float a1 = alf[c * OUT_F + 16 + fr];

    for (int tile = blockIdx.x * 2 + wave; tile * 16 < cnt; tile += GRIDX * 2) {
        int start = tile * 16;
        int nvalid = min(16, cnt - start);
        int j = min(fr, nvalid - 1);              // clamp: dup valid row, never stored
        int srow = (int)buckets[c * NB + start + j];   // this lane's m-row sample id
        const float* xr = x + (size_t)srow * IN_F + k0 + fq * 8;
        f32x4 acc0 = {0.f, 0.f, 0.f, 0.f};
        f32x4 acc1 = {0.f, 0.f, 0.f, 0.f};
        #pragma unroll
        for (int kk = 0; kk < 8; ++kk) {
            float4 v0 = *(const float4*)(xr + kk * 32);
            float4 v1 = *(const float4*)(xr + kk * 32 + 4);
            bf16x8 a = pack8(v0, v1);
            acc0 = __builtin_amdgcn_mfma_f32_16x16x32_bf16(a, Bf0[kk], acc0, 0, 0, 0);
            acc1 = __builtin_amdgcn_mfma_f32_16x16x32_bf16(a, Bf1[kk], acc1, 0, 0, 0);
        }
        #pragma unroll
        for (int reg = 0; reg < 4; ++reg) {
            int m = fq * 4 + reg;
            int sr = __shfl(srow, m);             // lane m holds row m's sample id
            if (m < nvalid) {
                atomicAdd(&out[(size_t)sr * OUT_F + fr],          acc0[reg] * a0);
                atomicAdd(&out[(size_t)sr * OUT_F + 16 + fr],     acc1[reg] * a1);
            }
        }
    }
}

// ---------------------------------------------------------------------------
extern "C" void kernel_launch(void* const* d_in, const int* in_sizes, int n_in,
                              void* d_out, int out_size, void* d_ws, size_t ws_size,
                              hipStream_t stream)
{
    (void)in_sizes; (void)n_in; (void)out_size; (void)ws_size;
    const float*        x      = (const float*)d_in[0];
    const unsigned int* ls     = (const unsigned int*)d_in[1];
    const float*        weight = (const float*)d_in[2];
    const float*        bias   = (const float*)d_in[3];
    const float*        law    = (const float*)d_in[4];
    float*              out    = (float*)d_out;

    char* ws = (char*)d_ws;
    int*            counts  = (int*)ws;                       // 32 B
    float*          alf     = (float*)(ws + 64);              // 1 KB
    unsigned short* wq      = (unsigned short*)(ws + 64 + 1024);          // 512 KB
    unsigned short* buckets = (unsigned short*)(ws + 64 + 1024 + 524288); // 128 KB

    hipMemsetAsync(counts, 0, NCLS * sizeof(int), stream);
    quantw_kernel<<<NCLS * OUT_F, 256, 0, stream>>>(weight, law, alf, wq);
    bucket_kernel<<<NB / 256, 256, 0, stream>>>(ls, bias, counts, buckets, out);
    gemm_kernel<<<dim3(GRIDX, NCLS, KSPLIT), 128, 0, stream>>>(
        x, alf, wq, counts, buckets, out);
}

// Round 3
// 92.704 us; speedup vs baseline: 1.3937x; 1.0386x over previous
//
#include <hip/hip_runtime.h>

// StackedLinear (LSQ-quantized, 8 classes x [32 x 1024]), B=8192.
// out[b,o] = alpha[c,o] * sum_i w_int[c,o,i] * x[b,i] + bias[c,o],  c = idx[b]
// w_int = rint(clip(w/alpha,-128,127)) in [-128,127] -> exact in bf16.
//
// R3: KSPLIT 4->8 (B-frag VGPRs 64->32, waves 3072->5120 = 5/SIMD),
//     quantw+bucket fused into one prep kernel (3 graph nodes total),
//     per-block-slice int64 detection (128 words vs 4096).
//
// Nodes: 1. memset counts  2. prep (quantize W + bucket + bias-init out)
//        3. gemm (split-K=8, no LDS, no barriers, atomicAdd epilogue)

#define IN_F   1024
#define OUT_F  32
#define NCLS   8
#define NB     8192
#define KSPLIT 8
#define KCH    (IN_F / KSPLIT)   // 128
#define GRIDX  40                // m-tile wave-slots: 80 per (c,kq); grid-stride

typedef __attribute__((ext_vector_type(8))) __bf16 bf16x8;
typedef __attribute__((ext_vector_type(4))) float  f32x4;

__device__ __forceinline__ unsigned short f2bf(float f) {
    unsigned int u = __builtin_bit_cast(unsigned int, f);
    u += 0x7FFFu + ((u >> 16) & 1u);
    return (unsigned short)(u >> 16);
}

__device__ __forceinline__ bf16x8 pack8(float4 v0, float4 v1) {
    union { unsigned short u[8]; bf16x8 v; } r;
    r.u[0] = f2bf(v0.x); r.u[1] = f2bf(v0.y); r.u[2] = f2bf(v0.z); r.u[3] = f2bf(v0.w);
    r.u[4] = f2bf(v1.x); r.u[5] = f2bf(v1.y); r.u[6] = f2bf(v1.z); r.u[7] = f2bf(v1.w);
    return r.v;
}

// ---------------------------------------------------------------------------
// Fused prep. Blocks 0..255: quantize weight row (c*32+o) -> bf16 wq + alpha.
// Blocks 256..287: bucket 256 samples by class + init out rows with bias.
__global__ __launch_bounds__(256) void prep_kernel(
    const float* __restrict__ weight, const float* __restrict__ law,
    const unsigned int* __restrict__ lsw, const float* __restrict__ bias,
    float* __restrict__ alf, unsigned short* __restrict__ wq,
    int* __restrict__ counts, unsigned short* __restrict__ buckets,
    float* __restrict__ out)
{
    int t = threadIdx.x;
    if (blockIdx.x < NCLS * OUT_F) {
        // ---- quantize one weight row
        int row = blockIdx.x;
        float a = expf(law[row]);
        if (t == 0) alf[row] = a;
        float4 v = ((const float4*)(weight + (size_t)row * IN_F))[t];
        ushort4 p;
        p.x = f2bf(rintf(fminf(fmaxf(v.x / a, -128.f), 127.f)));
        p.y = f2bf(rintf(fminf(fmaxf(v.y / a, -128.f), 127.f)));
        p.z = f2bf(rintf(fminf(fmaxf(v.z / a, -128.f), 127.f)));
        p.w = f2bf(rintf(fminf(fmaxf(v.w / a, -128.f), 127.f)));
        ((ushort4*)(wq + (size_t)row * IN_F))[t] = p;
        return;
    }
    // ---- bucket 256 samples
    int blk = blockIdx.x - NCLS * OUT_F;      // 0..31
    int b = blk * 256 + t;
    __shared__ int lcnt[NCLS];
    __shared__ int lbase[NCLS];
    __shared__ int s_is64;
    if (t < NCLS) lcnt[t] = 0;
    if (t == 0) s_is64 = 1;
    __syncthreads();
    // int64 detect on this block's 128-word slice of odd words (indices
    // 2i+1, i in [blk*128, blk*128+128) -> max word 8191, in-bounds either
    // width). int64 (vals 0..7) => all zero; int32 => P(all zero)=8^-128.
    if (t < 128) {
        if (lsw[2 * (blk * 128 + t) + 1] != 0u) atomicAnd(&s_is64, 0);
    }
    __syncthreads();
    int c = s_is64 ? (int)lsw[2 * b] : (int)lsw[b];
    // out[b][:] = bias[c][:]
    const float4* bb = (const float4*)(bias + c * OUT_F);
    float4* ob = (float4*)(out + (size_t)b * OUT_F);
    #pragma unroll
    for (int i = 0; i < OUT_F / 4; ++i) ob[i] = bb[i];
    int lpos = atomicAdd(&lcnt[c], 1);
    __syncthreads();
    if (t < NCLS) lbase[t] = atomicAdd(&counts[t], lcnt[t]);
    __syncthreads();
    buckets[c * NB + lbase[c] + lpos] = (unsigned short)b;
}

// ---------------------------------------------------------------------------
// Split-K GEMM, no LDS, no barriers. Block = 128 thr = 2 waves; each wave:
// m-tile of 16 samples, both n-halves (2 accs), K-chunk of 128.
// MFMA 16x16x32 bf16 layouts (verified R1/R2): A[m=lane&15][k=q*8+j],
// B^T[n=lane&15][k=q*8+j], D: n=lane&15, m=q*4+reg.
__global__ __launch_bounds__(128) void gemm_kernel(
    const float* __restrict__ x, const float* __restrict__ alf,
    const unsigned short* __restrict__ wq,
    const int* __restrict__ counts, const unsigned short* __restrict__ buckets,
    float* __restrict__ out)
{
    int c  = blockIdx.y;
    int kq = blockIdx.z;
    int cnt = counts[c];
    int t = threadIdx.x;
    int wave = t >> 6, lane = t & 63;
    int fr = lane & 15, fq = lane >> 4;
    int k0 = kq * KCH;

    // B fragments, both n-halves, 4 k-steps, in VGPRs (L2-hot loads)
    const unsigned short* wrow0 = wq + (size_t)(c * OUT_F + fr) * IN_F + k0 + fq * 8;
    const unsigned short* wrow1 = wrow0 + 16 * IN_F;
    bf16x8 Bf0[KCH / 32], Bf1[KCH / 32];
    #pragma unroll
    for (int kk = 0; kk < KCH / 32; ++kk) {
        Bf0[kk] = *(const bf16x8*)(wrow0 + kk * 32);
        Bf1[kk] = *(const bf16x8*)(wrow1 + kk * 32);
    }
    float a0 = alf[c * OUT_F + fr];
    float a1 = alf[c * OUT_F + 16 + fr];

    for (int tile = blockIdx.x * 2 + wave; tile * 16 < cnt; tile += GRIDX * 2) {
        int start = tile * 16;
        int nvalid = min(16, cnt - start);
        int j = min(fr, nvalid - 1);                 // clamp: dup valid row
        int srow = (int)buckets[c * NB + start + j]; // this lane's m-row sample
        const float* xr = x + (size_t)srow * IN_F + k0 + fq * 8;
        f32x4 acc0 = {0.f, 0.f, 0.f, 0.f};
        f32x4 acc1 = {0.f, 0.f, 0.f, 0.f};
        #pragma unroll
        for (int kk = 0; kk < KCH / 32; ++kk) {
            float4 v0 = *(const float4*)(xr + kk * 32);
            float4 v1 = *(const float4*)(xr + kk * 32 + 4);
            bf16x8 a = pack8(v0, v1);
            acc0 = __builtin_amdgcn_mfma_f32_16x16x32_bf16(a, Bf0[kk], acc0, 0, 0, 0);
            acc1 = __builtin_amdgcn_mfma_f32_16x16x32_bf16(a, Bf1[kk], acc1, 0, 0, 0);
        }
        #pragma unroll
        for (int reg = 0; reg < 4; ++reg) {
            int m = fq * 4 + reg;
            int sr = __shfl(srow, m);                // lane m holds row m's id
            if (m < nvalid) {
                atomicAdd(&out[(size_t)sr * OUT_F + fr],      acc0[reg] * a0);
                atomicAdd(&out[(size_t)sr * OUT_F + 16 + fr], acc1[reg] * a1);
            }
        }
    }
}

// ---------------------------------------------------------------------------
extern "C" void kernel_launch(void* const* d_in, const int* in_sizes, int n_in,
                              void* d_out, int out_size, void* d_ws, size_t ws_size,
                              hipStream_t stream)
{
    (void)in_sizes; (void)n_in; (void)out_size; (void)ws_size;
    const float*        x      = (const float*)d_in[0];
    const unsigned int* ls     = (const unsigned int*)d_in[1];
    const float*        weight = (const float*)d_in[2];
    const float*        bias   = (const float*)d_in[3];
    const float*        law    = (const float*)d_in[4];
    float*              out    = (float*)d_out;

    char* ws = (char*)d_ws;
    int*            counts  = (int*)ws;                                   // 32 B
    float*          alf     = (float*)(ws + 64);                          // 1 KB
    unsigned short* wq      = (unsigned short*)(ws + 64 + 1024);          // 512 KB
    unsigned short* buckets = (unsigned short*)(ws + 64 + 1024 + 524288); // 128 KB

    hipMemsetAsync(counts, 0, NCLS * sizeof(int), stream);
    prep_kernel<<<NCLS * OUT_F + NB / 256, 256, 0, stream>>>(
        weight, law, ls, bias, alf, wq, counts, buckets, out);
    gemm_kernel<<<dim3(GRIDX, NCLS, KSPLIT), 128, 0, stream>>>(
        x, alf, wq, counts, buckets, out);
}